// Round 1
// baseline (127.885 us; speedup 1.0000x reference)
//
#include <hip/hip_runtime.h>
#include <stdint.h>

#define B_   4096
#define T_   48
#define D_   35
#define H_   64
#define KROW 168   // LDS row stride (elements); MFMA K extent is 160 = 5*32
#define BT   16    // batch tile per block

typedef float f32x4 __attribute__((ext_vector_type(4)));
typedef short bf16x8 __attribute__((ext_vector_type(8)));

__device__ __forceinline__ float sigm(float z)  { return 1.0f / (1.0f + __expf(-z)); }
__device__ __forceinline__ float tanh_(float z) { return 2.0f / (1.0f + __expf(-2.0f * z)) - 1.0f; }
__device__ __forceinline__ unsigned short f2bf(float x) {
    union { float f; uint32_t u; } v; v.f = x;
    return (unsigned short)((v.u + 0x7fffu + ((v.u >> 16) & 1u)) >> 16);
}
__device__ __forceinline__ float bf2f(unsigned short b) {
    union { uint32_t u; float f; } v; v.u = ((uint32_t)b) << 16;
    return v.f;
}

// Pre-pass: msum[t] = sum over (b,d) of masks[b][t][d], accumulated atomically
// into ws[t] (ws zeroed by hipMemsetAsync each launch). Also zeroes out[0].
__global__ void pre_kernel(const float* __restrict__ masks, float* __restrict__ ws,
                           float* __restrict__ out)
{
    const int t     = blockIdx.x % T_;
    const int chunk = blockIdx.x / T_;   // 8 chunks of 512 batch rows
    const int tid   = threadIdx.x;
    if (blockIdx.x == 0 && tid == 0) out[0] = 0.0f;
    float s = 0.f;
    for (int idx = tid; idx < 512 * D_; idx += 256) {
        int b = chunk * 512 + idx / D_;
        int d = idx % D_;
        s += masks[(b * T_ + t) * D_ + d];
    }
    #pragma unroll
    for (int off = 32; off; off >>= 1) s += __shfl_down(s, off, 64);
    __shared__ float red[4];
    if ((tid & 63) == 0) red[tid >> 6] = s;
    __syncthreads();
    if (tid == 0) atomicAdd(&ws[t], red[0] + red[1] + red[2] + red[3]);
}

__global__ __launch_bounds__(256, 1)
void brits_main(const float* __restrict__ x_t, const float* __restrict__ masks,
                const float* __restrict__ W_ih, const float* __restrict__ W_hh,
                const float* __restrict__ b_ih, const float* __restrict__ b_hh,
                const float* __restrict__ W_reg, const float* __restrict__ b_reg,
                const float* __restrict__ W_out, const float* __restrict__ b_out,
                const float* __restrict__ msum_raw, float* __restrict__ out)
{
    // LDS: weights (bf16) + double-buffered A tile + small f32 tables. ~105 KB.
    __shared__ unsigned short Wt[256 * KROW];     // [n=gate 0..255][k 0..167]: k<70=W_ih, 72..135=W_hh, rest 0
    __shared__ unsigned short Wreg[48 * 72];      // [n 0..47][k 0..71] (rows >=35 zero)
    __shared__ unsigned short Abuf[2][BT * KROW]; // [r][k]: 0..34 x_c, 35..69 m, 72..135 h, rest 0
    __shared__ float bc[256];
    __shared__ float breg[48];
    __shared__ float wout[65];
    __shared__ float invms[48];
    __shared__ float redbuf[4];

    const int tid    = threadIdx.x;
    const int lane   = tid & 63;
    const int w      = tid >> 6;      // wave 0..3
    const int g      = lane >> 4;     // lane group 0..3
    const int cc     = lane & 15;
    const int batch0 = blockIdx.x * BT;
    const int u      = w * 16 + cc;   // this lane's hidden unit (P3) / x_hat col (P1, w<3)

    // ---- one-time staging ----
    {
        const int n = tid;  // 0..255
        for (int k = 0; k < 70; ++k) Wt[n * KROW + k] = f2bf(W_ih[n * 70 + k]);
        Wt[n * KROW + 70] = 0; Wt[n * KROW + 71] = 0;
        for (int k = 0; k < 64; ++k) Wt[n * KROW + 72 + k] = f2bf(W_hh[n * 64 + k]);
        for (int k = 136; k < KROW; ++k) Wt[n * KROW + k] = 0;
        bc[n] = b_ih[n] + b_hh[n];
    }
    if (tid < 48) {
        if (tid < 35) {
            for (int k = 0; k < 64; ++k) Wreg[tid * 72 + k] = f2bf(W_reg[tid * 64 + k]);
            for (int k = 64; k < 72; ++k) Wreg[tid * 72 + k] = 0;
            breg[tid] = b_reg[tid];
        } else {
            for (int k = 0; k < 72; ++k) Wreg[tid * 72 + k] = 0;
            breg[tid] = 0.f;
        }
        invms[tid] = 1.0f / (msum_raw[tid] + 1e-5f);
    }
    if (tid < 65) wout[tid] = (tid < 64) ? W_out[tid] : b_out[0];
    for (int i = tid; i < 2 * BT * KROW; i += 256) ((unsigned short*)Abuf)[i] = 0; // h0=0, pads=0
    __syncthreads();

    float c_reg[4] = {0.f, 0.f, 0.f, 0.f};
    float loss_acc = 0.f;

    for (int t = 0; t < T_; ++t) {
        unsigned short* A  = Abuf[t & 1];
        unsigned short* An = Abuf[(t + 1) & 1];

        // ---- P1: x_hat = h @ W_reg^T + b_reg; epilogue fills x_c/m, loss, imputations ----
        if (w < 3) {
            f32x4 acc = {0.f, 0.f, 0.f, 0.f};
            #pragma unroll
            for (int kk = 0; kk < 2; ++kk) {
                bf16x8 a = *(const bf16x8*)&A[cc * KROW + 72 + kk * 32 + 8 * g];
                bf16x8 b = *(const bf16x8*)&Wreg[u * 72 + kk * 32 + 8 * g];
                acc = __builtin_amdgcn_mfma_f32_16x16x32_bf16(a, b, acc, 0, 0, 0);
            }
            if (u < D_) {
                const float bb  = breg[u];
                const float inv = invms[t];
                #pragma unroll
                for (int j = 0; j < 4; ++j) {
                    int r  = 4 * g + j;
                    int gi = ((batch0 + r) * T_ + t) * D_ + u;
                    float x  = x_t[gi];
                    float m  = masks[gi];
                    float xh = acc[j] + bb;
                    float xc = m * x + (1.f - m) * xh;
                    loss_acc += fabsf(x - xh) * m * inv;
                    out[1 + B_ + gi] = xc;                 // imputations (f32)
                    A[r * KROW + u]      = f2bf(xc);
                    A[r * KROW + 35 + u] = f2bf(m);
                }
            }
        }
        __syncthreads();   // A[x_c|m] complete before gates matmul

        // ---- P2: gates = A @ Wcomb^T ; acc nt -> gate nt (i,f,g,o) for unit u ----
        f32x4 ai = {0,0,0,0}, af = {0,0,0,0}, ag = {0,0,0,0}, ao = {0,0,0,0};
        #pragma unroll
        for (int kk = 0; kk < 5; ++kk) {
            bf16x8 a  = *(const bf16x8*)&A[cc * KROW + kk * 32 + 8 * g];
            bf16x8 b0 = *(const bf16x8*)&Wt[(0 * 64 + u) * KROW + kk * 32 + 8 * g];
            bf16x8 b1 = *(const bf16x8*)&Wt[(1 * 64 + u) * KROW + kk * 32 + 8 * g];
            bf16x8 b2 = *(const bf16x8*)&Wt[(2 * 64 + u) * KROW + kk * 32 + 8 * g];
            bf16x8 b3 = *(const bf16x8*)&Wt[(3 * 64 + u) * KROW + kk * 32 + 8 * g];
            ai = __builtin_amdgcn_mfma_f32_16x16x32_bf16(a, b0, ai, 0, 0, 0);
            af = __builtin_amdgcn_mfma_f32_16x16x32_bf16(a, b1, af, 0, 0, 0);
            ag = __builtin_amdgcn_mfma_f32_16x16x32_bf16(a, b2, ag, 0, 0, 0);
            ao = __builtin_amdgcn_mfma_f32_16x16x32_bf16(a, b3, ao, 0, 0, 0);
        }

        // ---- P3: cell update in registers, write new h (bf16) into next buffer ----
        #pragma unroll
        for (int j = 0; j < 4; ++j) {
            float iv = sigm (ai[j] + bc[u]);
            float fv = sigm (af[j] + bc[64 + u]);
            float gv = tanh_(ag[j] + bc[128 + u]);
            float ov = sigm (ao[j] + bc[192 + u]);
            float cn = fv * c_reg[j] + iv * gv;
            c_reg[j] = cn;
            float hn = ov * tanh_(cn);
            An[(4 * g + j) * KROW + 72 + u] = f2bf(hn);
        }
        __syncthreads();   // h complete before next step reads it
    }

    // ---- loss reduction ----
    float v = loss_acc;
    #pragma unroll
    for (int off = 32; off; off >>= 1) v += __shfl_down(v, off, 64);
    if ((tid & 63) == 0) redbuf[w] = v;
    __syncthreads();
    if (tid == 0) atomicAdd(out, (redbuf[0] + redbuf[1] + redbuf[2] + redbuf[3]) * (1.0f / T_));

    // ---- y_h = sigmoid(h_final @ W_out^T + b_out) ; final h is in Abuf[0] ----
    if (w == 0) {
        const int r = cc;
        float p = 0.f;
        #pragma unroll
        for (int k = 0; k < 16; ++k)
            p += bf2f(Abuf[0][r * KROW + 72 + 16 * g + k]) * wout[16 * g + k];
        p += __shfl_xor(p, 16, 64);
        p += __shfl_xor(p, 32, 64);
        if (lane < 16) out[1 + batch0 + r] = sigm(p + wout[64]);
    }
}

extern "C" void kernel_launch(void* const* d_in, const int* in_sizes, int n_in,
                              void* d_out, int out_size, void* d_ws, size_t ws_size,
                              hipStream_t stream) {
    const float* x_t   = (const float*)d_in[0];
    const float* masks = (const float*)d_in[1];
    // d_in[2] deltas, d_in[3] evals, d_in[4] eval_masks, d_in[5] is_train: unused
    const float* W_ih  = (const float*)d_in[6];
    const float* W_hh  = (const float*)d_in[7];
    const float* b_ih  = (const float*)d_in[8];
    const float* b_hh  = (const float*)d_in[9];
    const float* W_reg = (const float*)d_in[10];
    const float* b_reg = (const float*)d_in[11];
    const float* W_out = (const float*)d_in[14];
    const float* b_out = (const float*)d_in[15];
    float* out = (float*)d_out;
    float* ws  = (float*)d_ws;

    hipMemsetAsync(ws, 0, T_ * sizeof(float), stream);
    pre_kernel<<<T_ * 8, 256, 0, stream>>>(masks, ws, out);
    brits_main<<<B_ / BT, 256, 0, stream>>>(x_t, masks, W_ih, W_hh, b_ih, b_hh,
                                            W_reg, b_reg, W_out, b_out, ws, out);
}